// Round 8
// baseline (411.141 us; speedup 1.0000x reference)
//
#include <hip/hip_runtime.h>
#include <hip/hip_bf16.h>
#include <cstdint>
#include <cstddef>

#define T_TOK 4096
#define DIM   1024
#define IDIM  1024
#define NEXP  32
#define TOPK  4
#define MAXT  160            // max 128-row m-tiles (128 full + <=32 pad)
#define RPAD  (MAXT*128)     // 20480 padded rows max

typedef short sh8   __attribute__((ext_vector_type(8)));
typedef float f32x4 __attribute__((ext_vector_type(4)));

__device__ __forceinline__ short bf(float f) {
    union { float f; uint32_t u; } v; v.f = f;
    uint32_t r = (v.u + 0x7FFFu + ((v.u >> 16) & 1u)) >> 16;   // RNE
    return (short)r;
}
__device__ __forceinline__ sh8 pack8(float4 a, float4 b) {
    sh8 r;
    r[0]=bf(a.x); r[1]=bf(a.y); r[2]=bf(a.z); r[3]=bf(a.w);
    r[4]=bf(b.x); r[5]=bf(b.y); r[6]=bf(b.z); r[7]=bf(b.w);
    return r;
}
// fp32 pair -> packed 2x bf16 (RNE), gfx950
__device__ __forceinline__ uint32_t cvtpk(float lo, float hi) {
    uint32_t r;
    asm("v_cvt_pk_bf16_f32 %0, %1, %2" : "=v"(r) : "v"(lo), "v"(hi));
    return r;
}
__device__ __forceinline__ sh8 cvt8(f32x4 a, f32x4 b) {
    union { uint32_t u[4]; sh8 s; } v;
    v.u[0] = cvtpk(a[0], a[1]); v.u[1] = cvtpk(a[2], a[3]);
    v.u[2] = cvtpk(b[0], b[1]); v.u[3] = cvtpk(b[2], b[3]);
    return v.s;
}
__device__ __forceinline__ void glds16(const void* g, const void* l) {
    __builtin_amdgcn_global_load_lds((const __attribute__((address_space(1))) void*)g,
                                     (__attribute__((address_space(3))) void*)l, 16, 0, 0);
}

// row-tile -> expert map (gather): which expert owns m-tile `mt`
__device__ __forceinline__ int tile_expert(const int* __restrict__ cnt, int mt, int& tile_start) {
    int s = 0, e = -1, ts = 0;
    #pragma unroll
    for (int i = 0; i < NEXP; ++i) {
        int t = (cnt[i] + 127) >> 7;
        if (mt >= s && mt < s + t) { e = i; ts = s; }
        s += t;
    }
    tile_start = ts;
    return e;
}

// WEIGHT-MAJOR block decode: blocks sharing a weight slab (e,nt) are consecutive
// -> same XCD under chunked swizzle -> slab read once from HBM, L2-reused.
__device__ __forceinline__ bool decode_wmajor(const int* __restrict__ cnt, int bid, int ntsz,
                                              int& e, int& mt, int& nt) {
    int base = 0, tacc = 0, fe = -1, floc = 0, fts = 0, fntl = 1;
    #pragma unroll
    for (int i = 0; i < NEXP; ++i) {
        int ntl = (cnt[i] + 127) >> 7;
        int sz  = ntsz * ntl;
        if (bid >= base && bid < base + sz) { fe = i; floc = bid - base; fts = tacc; fntl = ntl; }
        base += sz; tacc += ntl;
    }
    if (fe < 0) return false;
    e  = fe;
    nt = floc / fntl;
    mt = fts + (floc % fntl);
    return true;
}

// ---------------- Router: one wave per token, fp32 ----------------
__global__ __launch_bounds__(256) void router_kernel(
    const float* __restrict__ X, const float* __restrict__ GW,
    const float* __restrict__ bias, int* __restrict__ topk_idx,
    float* __restrict__ topk_w, int* __restrict__ cnt,
    int* __restrict__ tlist_c, int* __restrict__ posmap)
{
    int wid  = threadIdx.x >> 6;
    int lane = threadIdx.x & 63;
    int t = blockIdx.x * 4 + wid;

    float4 h[4];
    const float4* xr = reinterpret_cast<const float4*>(X + (size_t)t * DIM);
    #pragma unroll
    for (int c = 0; c < 4; ++c) h[c] = xr[lane + 64 * c];

    float myscore = 0.f;
    for (int e = 0; e < NEXP; ++e) {
        const float4* gr = reinterpret_cast<const float4*>(GW + (size_t)e * DIM);
        float p = 0.f;
        #pragma unroll
        for (int c = 0; c < 4; ++c) {
            float4 g = gr[lane + 64 * c];
            p += h[c].x * g.x + h[c].y * g.y + h[c].z * g.z + h[c].w * g.w;
        }
        #pragma unroll
        for (int o = 32; o; o >>= 1) p += __shfl_xor(p, o);
        if (lane == e) myscore = p;
    }
    float rw = 1.f / (1.f + expf(-myscore));
    float sel = (lane < NEXP) ? rw + bias[lane] : -1e30f;

    float wsum = 0.f;
    int   oi = 0; float ow = 0.f;
    #pragma unroll
    for (int k = 0; k < TOPK; ++k) {
        float v = sel;
        int   idx = (lane < NEXP) ? lane : 9999;
        #pragma unroll
        for (int o = 32; o; o >>= 1) {
            float v2 = __shfl_xor(v, o);
            int   i2 = __shfl_xor(idx, o);
            if (v2 > v || (v2 == v && i2 < idx)) { v = v2; idx = i2; }
        }
        float wk = __shfl(rw, idx);
        wsum += wk;
        if (lane == k)   { oi = idx; ow = wk; }
        if (lane == idx) sel = -1e30f;
    }
    if (lane < TOPK) {
        int gid = t * TOPK + lane;
        topk_idx[gid] = oi;
        topk_w  [gid] = ow / (wsum + 1e-6f);
        int pos = atomicAdd(&cnt[oi], 1);   // order-nondeterministic; consumption is order-invariant
        tlist_c[oi * T_TOK + pos] = t;
        posmap[gid] = pos;
    }
}

// ---------------- Gather: build padded Xg bf16 ----------------
__global__ __launch_bounds__(256) void gather_kernel(
    const float* __restrict__ X, const int* __restrict__ cnt,
    const int* __restrict__ tlist_c, short* __restrict__ Xg)
{
    int wid = threadIdx.x >> 6, lane = threadIdx.x & 63;
    int r = blockIdx.x * 4 + wid;
    int ts;
    int e = tile_expert(cnt, r >> 7, ts);
    if (e < 0) return;
    int li = r - (ts << 7);
    bool real = li < cnt[e];
    int t = real ? tlist_c[e * T_TOK + li] : 0;
    const float4* src = reinterpret_cast<const float4*>(X + (size_t)t * DIM);
    sh8* dst = reinterpret_cast<sh8*>(Xg + (size_t)r * DIM);
    float4 z = make_float4(0.f, 0.f, 0.f, 0.f);
    #pragma unroll
    for (int it = 0; it < 2; ++it) {
        int si = it * 64 + lane;
        float4 a = real ? src[2 * si]     : z;
        float4 b = real ? src[2 * si + 1] : z;
        dst[si] = pack8(a, b);
    }
}

// ---------------- GEMM1: Xg @ Wgu^T (g,u fused), silu, H bf16 ----------------
// 128(M) x 64(N, x2 g/u), BK=64. A: bf16 glds16 (pre-swizzled source, proven).
// B: fp32 global -> regs issued ONE K-STEP EARLY (latency hidden under MFMA phase,
// T14 async-stage) -> v_cvt_pk_bf16_f32 -> swizzled ds_write_b128 -> bf16 LDS.
// LDS all-bf16: 32 KB/block. Two barriers/K-step (m97 regime, 3 blocks/CU).
__global__ __launch_bounds__(256, 3) void gemm1_kernel(
    const short* __restrict__ Xg, const float* __restrict__ GUP,
    const int* __restrict__ cnt, short* __restrict__ H)
{
    int bid = (blockIdx.x & 7) * (MAXT * 16 / 8) + (blockIdx.x >> 3);
    int e, mt, nt;
    if (!decode_wmajor(cnt, bid, 16, e, mt, nt)) return;
    int m0 = mt * 128, n0 = nt * 64;

    __shared__ short As[128 * 64];   // 16 KB
    __shared__ short Bg[64 * 64];    // 8 KB
    __shared__ short Bu[64 * 64];    // 8 KB

    int tid = threadIdx.x, lane = tid & 63, wv = tid >> 6;
    int wm = (wv >> 1) * 64, wn = (wv & 1) * 32;

    f32x4 accg[4][2] = {};
    f32x4 accu[4][2] = {};

    int swcolA = ((lane & 7) ^ (lane >> 3)) * 8;   // A pre-swizzled source col (bf16 elems)
    int brow = tid >> 2, bcol = (tid & 3) * 16;    // B: 64 rows x 4 threads, 16 f32 cols each
    int bsw  = (brow & 7) << 3;
    const float* gp = GUP + ((size_t)e * 2 * IDIM + n0 + brow) * DIM + bcol;
    const float* up = gp + (size_t)IDIM * DIM;

    f32x4 bg[4], bu[4];
    auto loadB = [&](int k0) {
        #pragma unroll
        for (int j = 0; j < 4; ++j) bg[j] = *reinterpret_cast<const f32x4*>(gp + k0 + j * 4);
        #pragma unroll
        for (int j = 0; j < 4; ++j) bu[j] = *reinterpret_cast<const f32x4*>(up + k0 + j * 4);
    };
    auto writeB = [&]() {
        *reinterpret_cast<sh8*>(&Bg[brow * 64 + ( bcol      ^ bsw)]) = cvt8(bg[0], bg[1]);
        *reinterpret_cast<sh8*>(&Bg[brow * 64 + ((bcol + 8) ^ bsw)]) = cvt8(bg[2], bg[3]);
        *reinterpret_cast<sh8*>(&Bu[brow * 64 + ( bcol      ^ bsw)]) = cvt8(bu[0], bu[1]);
        *reinterpret_cast<sh8*>(&Bu[brow * 64 + ((bcol + 8) ^ bsw)]) = cvt8(bu[2], bu[3]);
    };

    int swr = (lane & 7) << 3;
    loadB(0);
    for (int it = 0; it < DIM / 64; ++it) {
        int k0 = it * 64;
        #pragma unroll
        for (int j = 0; j < 4; ++j) {            // A: glds direct, 8 rows/call
            int ch = wv * 4 + j;
            glds16(Xg + (size_t)(m0 + ch * 8 + (lane >> 3)) * DIM + k0 + swcolA, &As[ch * 512]);
        }
        writeB();                                 // cvt + swizzled ds_write (B regs ready)
        __syncthreads();                          // drains A glds + B ds_writes
        if (it + 1 < DIM / 64) loadB(k0 + 64);    // issue next B early; waits at next barrier
        #pragma unroll
        for (int kk = 0; kk < 64; kk += 32) {
            int ki = (kk + (lane >> 4) * 8) ^ swr;
            sh8 af[4], gf[2], uf[2];
            #pragma unroll
            for (int fm = 0; fm < 4; ++fm)
                af[fm] = *reinterpret_cast<const sh8*>(&As[(wm + fm * 16 + (lane & 15)) * 64 + ki]);
            #pragma unroll
            for (int fn = 0; fn < 2; ++fn) {
                gf[fn] = *reinterpret_cast<const sh8*>(&Bg[(wn + fn * 16 + (lane & 15)) * 64 + ki]);
                uf[fn] = *reinterpret_cast<const sh8*>(&Bu[(wn + fn * 16 + (lane & 15)) * 64 + ki]);
            }
            #pragma unroll
            for (int fm = 0; fm < 4; ++fm)
                #pragma unroll
                for (int fn = 0; fn < 2; ++fn) {
                    accg[fm][fn] = __builtin_amdgcn_mfma_f32_16x16x32_bf16(af[fm], gf[fn], accg[fm][fn], 0, 0, 0);
                    accu[fm][fn] = __builtin_amdgcn_mfma_f32_16x16x32_bf16(af[fm], uf[fn], accu[fm][fn], 0, 0, 0);
                }
        }
        __syncthreads();
    }

    #pragma unroll
    for (int fm = 0; fm < 4; ++fm)
        #pragma unroll
        for (int r = 0; r < 4; ++r) {
            int row = m0 + wm + fm * 16 + (lane >> 4) * 4 + r;
            #pragma unroll
            for (int fn = 0; fn < 2; ++fn) {
                int col = n0 + wn + fn * 16 + (lane & 15);
                float g = accg[fm][fn][r];
                float u = accu[fm][fn][r];
                H[(size_t)row * IDIM + col] = bf(g / (1.f + expf(-g)) * u);
            }
        }
}

// ---------------- GEMM2: H @ Wd^T -> Y fp32 (no atomics) ----------------
// 128x128 tile, BK=64. A (H bf16) glds; B (Wd fp32) async reg-staged -> bf16 LDS.
__global__ __launch_bounds__(256, 3) void gemm2_kernel(
    const short* __restrict__ H, const float* __restrict__ DP,
    const int* __restrict__ cnt, float* __restrict__ Yf)
{
    int bid = (blockIdx.x & 7) * (MAXT * 8 / 8) + (blockIdx.x >> 3);
    int e, mt, nt;
    if (!decode_wmajor(cnt, bid, 8, e, mt, nt)) return;
    int m0 = mt * 128, n0 = nt * 128;

    __shared__ short As[128 * 64];   // 16 KB
    __shared__ short Bs[128 * 64];   // 16 KB

    int tid = threadIdx.x, lane = tid & 63, wv = tid >> 6;
    int wm = (wv >> 1) * 64, wn = (wv & 1) * 64;

    f32x4 acc[4][4] = {};

    int swcolA = ((lane & 7) ^ (lane >> 3)) * 8;
    int brow = tid >> 1, bcol = (tid & 1) * 32;    // 128 rows x 2 threads, 32 f32 cols each
    int bsw  = (brow & 7) << 3;
    const float* dp = DP + ((size_t)e * DIM + n0 + brow) * IDIM + bcol;

    f32x4 bd[8];
    auto loadB = [&](int k0) {
        #pragma unroll
        for (int j = 0; j < 8; ++j) bd[j] = *reinterpret_cast<const f32x4*>(dp + k0 + j * 4);
    };
    auto writeB = [&]() {
        #pragma unroll
        for (int j = 0; j < 4; ++j)
            *reinterpret_cast<sh8*>(&Bs[brow * 64 + ((bcol + j * 8) ^ bsw)]) = cvt8(bd[2*j], bd[2*j+1]);
    };

    int swr = (lane & 7) << 3;
    loadB(0);
    for (int it = 0; it < IDIM / 64; ++it) {
        int k0 = it * 64;
        #pragma unroll
        for (int j = 0; j < 4; ++j) {
            int ch = wv * 4 + j;
            glds16(H + (size_t)(m0 + ch * 8 + (lane >> 3)) * IDIM + k0 + swcolA, &As[ch * 512]);
        }
        writeB();
        __syncthreads();
        if (it + 1 < IDIM / 64) loadB(k0 + 64);
        #pragma unroll
        for (int kk = 0; kk < 64; kk += 32) {
            int ki = (kk + (lane >> 4) * 8) ^ swr;
            sh8 af[4], bq[4];
            #pragma unroll
            for (int fm = 0; fm < 4; ++fm)
                af[fm] = *reinterpret_cast<const sh8*>(&As[(wm + fm * 16 + (lane & 15)) * 64 + ki]);
            #pragma unroll
            for (int fn = 0; fn < 4; ++fn)
                bq[fn] = *reinterpret_cast<const sh8*>(&Bs[(wn + fn * 16 + (lane & 15)) * 64 + ki]);
            #pragma unroll
            for (int fm = 0; fm < 4; ++fm)
                #pragma unroll
                for (int fn = 0; fn < 4; ++fn)
                    acc[fm][fn] = __builtin_amdgcn_mfma_f32_16x16x32_bf16(af[fm], bq[fn], acc[fm][fn], 0, 0, 0);
        }
        __syncthreads();
    }

    #pragma unroll
    for (int fm = 0; fm < 4; ++fm)
        #pragma unroll
        for (int r = 0; r < 4; ++r) {
            int row = m0 + wm + fm * 16 + (lane >> 4) * 4 + r;
            #pragma unroll
            for (int fn = 0; fn < 4; ++fn) {
                int col = n0 + wn + fn * 16 + (lane & 15);
                Yf[(size_t)row * DIM + col] = acc[fm][fn][r];
            }
        }
}

// ---------------- Combine: out[t] = sum_k w_k * Y[row(t,k)] ----------------
__global__ __launch_bounds__(256) void combine_kernel(
    const float* __restrict__ Yf, const int* __restrict__ cnt,
    const int* __restrict__ topk_idx, const float* __restrict__ topk_w,
    const int* __restrict__ posmap, float* __restrict__ out)
{
    int t = blockIdx.x;
    int d = threadIdx.x * 4;
    int es[TOPK], rows[TOPK];
    #pragma unroll
    for (int k = 0; k < TOPK; ++k) es[k] = topk_idx[t * TOPK + k];
    int p = 0;
    #pragma unroll
    for (int i = 0; i < NEXP; ++i) {
        #pragma unroll
        for (int k = 0; k < TOPK; ++k)
            if (es[k] == i) rows[k] = p + posmap[t * TOPK + k];
        p += ((cnt[i] + 127) >> 7) << 7;
    }
    float4 acc = make_float4(0.f, 0.f, 0.f, 0.f);
    #pragma unroll
    for (int k = 0; k < TOPK; ++k) {
        float w = topk_w[t * TOPK + k];
        float4 y = *reinterpret_cast<const float4*>(Yf + (size_t)rows[k] * DIM + d);
        acc.x += w * y.x; acc.y += w * y.y; acc.z += w * y.z; acc.w += w * y.w;
    }
    *reinterpret_cast<float4*>(out + (size_t)t * DIM + d) = acc;
}

// ---------------- launch ----------------
extern "C" void kernel_launch(void* const* d_in, const int* in_sizes, int n_in,
                              void* d_out, int out_size, void* d_ws, size_t ws_size,
                              hipStream_t stream)
{
    const float* X    = (const float*)d_in[0];
    const float* GW   = (const float*)d_in[1];
    const float* GUP  = (const float*)d_in[2];
    const float* DP   = (const float*)d_in[3];
    const float* BIAS = (const float*)d_in[4];
    float* out = (float*)d_out;

    char* ws = (char*)d_ws;
    int*   cnt      = (int*)ws;                       // 128 B
    int*   topk_idx = (int*)(ws + (4u   << 10));      // 64 KB
    float* topk_w   = (float*)(ws + (68u  << 10));    // 64 KB
    int*   posmap   = (int*)(ws + (132u << 10));      // 64 KB
    int*   tlist_c  = (int*)(ws + (196u << 10));      // 512 KB

    constexpr size_t OFF_H  = 2ull << 20;
    constexpr size_t SZ_BF  = (size_t)RPAD * IDIM * 2;   // 40 MB
    constexpr size_t OFF_XG = OFF_H + SZ_BF;             // 42 MB
    constexpr size_t OFF_YF = OFF_XG + SZ_BF;            // 82 MB

    short* H  = (short*)(ws + OFF_H);
    short* Xg = (short*)(ws + OFF_XG);
    float* Yf = (float*)(ws + OFF_YF);

    (void)hipMemsetAsync(cnt, 0, 128, stream);

    router_kernel<<<T_TOK / 4, 256, 0, stream>>>(X, GW, BIAS, topk_idx, topk_w,
                                                 cnt, tlist_c, posmap);
    gather_kernel<<<RPAD / 4, 256, 0, stream>>>(X, cnt, tlist_c, Xg);

    gemm1_kernel<<<MAXT * 16, 256, 0, stream>>>(Xg, GUP, cnt, H);      // 2560 blocks
    gemm2_kernel<<<MAXT * 8,  256, 0, stream>>>(H, DP, cnt, Yf);       // 1280 blocks

    combine_kernel<<<T_TOK, 256, 0, stream>>>(Yf, cnt, topk_idx, topk_w, posmap, out);
}

// Round 9
// 329.311 us; speedup vs baseline: 1.2485x; 1.2485x over previous
//
#include <hip/hip_runtime.h>
#include <hip/hip_bf16.h>
#include <cstdint>
#include <cstddef>

#define T_TOK 4096
#define DIM   1024
#define IDIM  1024
#define NEXP  32
#define TOPK  4
#define MAXT  160            // max 128-row m-tiles (128 full + <=32 pad)
#define RPAD  (MAXT*128)     // 20480 padded rows max

typedef short sh8   __attribute__((ext_vector_type(8)));
typedef float f32x4 __attribute__((ext_vector_type(4)));

__device__ __forceinline__ short bf(float f) {
    union { float f; uint32_t u; } v; v.f = f;
    uint32_t r = (v.u + 0x7FFFu + ((v.u >> 16) & 1u)) >> 16;   // RNE
    return (short)r;
}
__device__ __forceinline__ sh8 pack8(float4 a, float4 b) {
    sh8 r;
    r[0]=bf(a.x); r[1]=bf(a.y); r[2]=bf(a.z); r[3]=bf(a.w);
    r[4]=bf(b.x); r[5]=bf(b.y); r[6]=bf(b.z); r[7]=bf(b.w);
    return r;
}
// fp32 pair -> packed 2x bf16 (RNE), gfx950
__device__ __forceinline__ uint32_t cvtpk(float lo, float hi) {
    uint32_t r;
    asm("v_cvt_pk_bf16_f32 %0, %1, %2" : "=v"(r) : "v"(lo), "v"(hi));
    return r;
}
__device__ __forceinline__ sh8 cvt8(f32x4 a, f32x4 b) {
    union { uint32_t u[4]; sh8 s; } v;
    v.u[0] = cvtpk(a[0], a[1]); v.u[1] = cvtpk(a[2], a[3]);
    v.u[2] = cvtpk(b[0], b[1]); v.u[3] = cvtpk(b[2], b[3]);
    return v.s;
}
__device__ __forceinline__ void glds16(const void* g, const void* l) {
    __builtin_amdgcn_global_load_lds((const __attribute__((address_space(1))) void*)g,
                                     (__attribute__((address_space(3))) void*)l, 16, 0, 0);
}

// row-tile -> expert map (gather): which expert owns m-tile `mt`
__device__ __forceinline__ int tile_expert(const int* __restrict__ cnt, int mt, int& tile_start) {
    int s = 0, e = -1, ts = 0;
    #pragma unroll
    for (int i = 0; i < NEXP; ++i) {
        int t = (cnt[i] + 127) >> 7;
        if (mt >= s && mt < s + t) { e = i; ts = s; }
        s += t;
    }
    tile_start = ts;
    return e;
}

// Balanced bijective XCD chunking (m204): hw block -> logical bid such that each
// XCD gets a CONTIGUOUS logical chunk of ~total/8 (slab L2-affinity preserved)
// and idle blocks spread evenly across XCDs (fixes the idle-XCD-7 tail).
__device__ __forceinline__ int balanced_bid(const int* __restrict__ cnt, int ntsz) {
    int tb = 0;
    #pragma unroll
    for (int i = 0; i < NEXP; ++i) tb += (cnt[i] + 127) >> 7;
    int total = tb * ntsz;
    int q = total >> 3, r = total & 7;
    int xcd = (int)blockIdx.x & 7, pos = (int)blockIdx.x >> 3;
    int cap = q + (xcd < r ? 1 : 0);
    if (pos >= cap) return -1;
    return (xcd < r ? xcd * (q + 1) : r * (q + 1) + (xcd - r) * q) + pos;
}

// WEIGHT-MAJOR block decode: blocks sharing a weight slab (e,nt) are consecutive.
__device__ __forceinline__ bool decode_wmajor(const int* __restrict__ cnt, int bid, int ntsz,
                                              int& e, int& mt, int& nt) {
    int base = 0, tacc = 0, fe = -1, floc = 0, fts = 0, fntl = 1;
    #pragma unroll
    for (int i = 0; i < NEXP; ++i) {
        int ntl = (cnt[i] + 127) >> 7;
        int sz  = ntsz * ntl;
        if (bid >= base && bid < base + sz) { fe = i; floc = bid - base; fts = tacc; fntl = ntl; }
        base += sz; tacc += ntl;
    }
    if (fe < 0) return false;
    e  = fe;
    nt = floc / fntl;
    mt = fts + (floc % fntl);
    return true;
}

// ---------------- Router: one wave per token, fp32 ----------------
__global__ __launch_bounds__(256) void router_kernel(
    const float* __restrict__ X, const float* __restrict__ GW,
    const float* __restrict__ bias, int* __restrict__ topk_idx,
    float* __restrict__ topk_w, int* __restrict__ cnt,
    int* __restrict__ tlist_c, int* __restrict__ posmap)
{
    int wid  = threadIdx.x >> 6;
    int lane = threadIdx.x & 63;
    int t = blockIdx.x * 4 + wid;

    float4 h[4];
    const float4* xr = reinterpret_cast<const float4*>(X + (size_t)t * DIM);
    #pragma unroll
    for (int c = 0; c < 4; ++c) h[c] = xr[lane + 64 * c];

    float myscore = 0.f;
    for (int e = 0; e < NEXP; ++e) {
        const float4* gr = reinterpret_cast<const float4*>(GW + (size_t)e * DIM);
        float p = 0.f;
        #pragma unroll
        for (int c = 0; c < 4; ++c) {
            float4 g = gr[lane + 64 * c];
            p += h[c].x * g.x + h[c].y * g.y + h[c].z * g.z + h[c].w * g.w;
        }
        #pragma unroll
        for (int o = 32; o; o >>= 1) p += __shfl_xor(p, o);
        if (lane == e) myscore = p;
    }
    float rw = 1.f / (1.f + expf(-myscore));
    float sel = (lane < NEXP) ? rw + bias[lane] : -1e30f;

    float wsum = 0.f;
    int   oi = 0; float ow = 0.f;
    #pragma unroll
    for (int k = 0; k < TOPK; ++k) {
        float v = sel;
        int   idx = (lane < NEXP) ? lane : 9999;
        #pragma unroll
        for (int o = 32; o; o >>= 1) {
            float v2 = __shfl_xor(v, o);
            int   i2 = __shfl_xor(idx, o);
            if (v2 > v || (v2 == v && i2 < idx)) { v = v2; idx = i2; }
        }
        float wk = __shfl(rw, idx);
        wsum += wk;
        if (lane == k)   { oi = idx; ow = wk; }
        if (lane == idx) sel = -1e30f;
    }
    if (lane < TOPK) {
        int gid = t * TOPK + lane;
        topk_idx[gid] = oi;
        topk_w  [gid] = ow / (wsum + 1e-6f);
        int pos = atomicAdd(&cnt[oi], 1);   // order-nondeterministic; consumption is order-invariant
        tlist_c[oi * T_TOK + pos] = t;
        posmap[gid] = pos;
    }
}

// ---------------- Gather: build padded Xg bf16 ----------------
__global__ __launch_bounds__(256) void gather_kernel(
    const float* __restrict__ X, const int* __restrict__ cnt,
    const int* __restrict__ tlist_c, short* __restrict__ Xg)
{
    int wid = threadIdx.x >> 6, lane = threadIdx.x & 63;
    int r = blockIdx.x * 4 + wid;
    int ts;
    int e = tile_expert(cnt, r >> 7, ts);
    if (e < 0) return;
    int li = r - (ts << 7);
    bool real = li < cnt[e];
    int t = real ? tlist_c[e * T_TOK + li] : 0;
    const float4* src = reinterpret_cast<const float4*>(X + (size_t)t * DIM);
    sh8* dst = reinterpret_cast<sh8*>(Xg + (size_t)r * DIM);
    float4 z = make_float4(0.f, 0.f, 0.f, 0.f);
    #pragma unroll
    for (int it = 0; it < 2; ++it) {
        int si = it * 64 + lane;
        float4 a = real ? src[2 * si]     : z;
        float4 b = real ? src[2 * si + 1] : z;
        dst[si] = pack8(a, b);
    }
}

// ---------------- GEMM1: Xg @ Wgu^T (g,u fused), silu, H bf16 ----------------
// R7 structure (proven best): A bf16 glds16; B fp32 glds16 direct to LDS,
// cvt_pk at fragment read. Changes vs R7: balanced XCD chunking; B swizzle
// key widened to 4 bits (r&15) on BOTH glds source and read index.
__global__ __launch_bounds__(256, 3) void gemm1_kernel(
    const short* __restrict__ Xg, const float* __restrict__ GUP,
    const int* __restrict__ cnt, short* __restrict__ H)
{
    int bid = balanced_bid(cnt, 16);
    if (bid < 0) return;
    int e, mt, nt;
    if (!decode_wmajor(cnt, bid, 16, e, mt, nt)) return;
    int m0 = mt * 128, n0 = nt * 64;

    __shared__ short As[128 * 64];   // 16 KB bf16
    __shared__ float Bg[64 * 64];    // 16 KB fp32
    __shared__ float Bu[64 * 64];    // 16 KB fp32

    int tid = threadIdx.x, lane = tid & 63, wv = tid >> 6;
    int wm = (wv >> 1) * 64, wn = (wv & 1) * 32;

    f32x4 accg[4][2] = {};
    f32x4 accu[4][2] = {};

    int swcolA = ((lane & 7) ^ (lane >> 3)) * 8;   // A pre-swizzled source col (bf16 elems)
    const float* gbase = GUP + ((size_t)e * 2 * IDIM + n0) * DIM;
    const float* ubase = gbase + (size_t)IDIM * DIM;

    auto stage = [&](int k0) {
        #pragma unroll
        for (int j = 0; j < 4; ++j) {            // A: 4 calls/wave, 8 rows/call
            int ch = wv * 4 + j;
            glds16(Xg + (size_t)(m0 + ch * 8 + (lane >> 3)) * DIM + k0 + swcolA, &As[ch * 512]);
        }
        #pragma unroll
        for (int j = 0; j < 4; ++j) {            // Bg/Bu: 4 calls/wave each, 4 rows/call
            int ch = wv * 4 + j;
            int r  = ch * 4 + (lane >> 4);
            int sc = ((lane & 15) ^ (r & 15)) << 2;   // 4-bit involution over 16 chunks/row
            glds16(gbase + (size_t)r * DIM + k0 + sc, &Bg[ch * 256]);
            glds16(ubase + (size_t)r * DIM + k0 + sc, &Bu[ch * 256]);
        }
    };

    int swrA = (lane & 7) << 3;
    int rx   = lane & 15;                         // R&15 for B-frag rows (R = wn+fn*16+(lane&15))
    for (int it = 0; it < DIM / 64; ++it) {
        stage(it * 64);
        __syncthreads();                          // vmcnt(0) drained here by compiler
        #pragma unroll
        for (int kk = 0; kk < 64; kk += 32) {
            int kiA = (kk + (lane >> 4) * 8) ^ swrA;
            sh8 af[4], gf[2], uf[2];
            #pragma unroll
            for (int fm = 0; fm < 4; ++fm)
                af[fm] = *reinterpret_cast<const sh8*>(&As[(wm + fm * 16 + (lane & 15)) * 64 + kiA]);
            int c0 = (kk >> 2) + (lane >> 4) * 2;         // 16B-chunk index within row (even)
            #pragma unroll
            for (int fn = 0; fn < 2; ++fn) {
                int R = wn + fn * 16 + (lane & 15);
                const float* bg = &Bg[R * 64];
                f32x4 lo = *reinterpret_cast<const f32x4*>(&bg[(c0       ^ rx) << 2]);
                f32x4 hi = *reinterpret_cast<const f32x4*>(&bg[((c0 + 1) ^ rx) << 2]);
                gf[fn] = cvt8(lo, hi);
                const float* bu = &Bu[R * 64];
                lo = *reinterpret_cast<const f32x4*>(&bu[(c0       ^ rx) << 2]);
                hi = *reinterpret_cast<const f32x4*>(&bu[((c0 + 1) ^ rx) << 2]);
                uf[fn] = cvt8(lo, hi);
            }
            #pragma unroll
            for (int fm = 0; fm < 4; ++fm)
                #pragma unroll
                for (int fn = 0; fn < 2; ++fn) {
                    accg[fm][fn] = __builtin_amdgcn_mfma_f32_16x16x32_bf16(af[fm], gf[fn], accg[fm][fn], 0, 0, 0);
                    accu[fm][fn] = __builtin_amdgcn_mfma_f32_16x16x32_bf16(af[fm], uf[fn], accu[fm][fn], 0, 0, 0);
                }
        }
        __syncthreads();
    }

    #pragma unroll
    for (int fm = 0; fm < 4; ++fm)
        #pragma unroll
        for (int r = 0; r < 4; ++r) {
            int row = m0 + wm + fm * 16 + (lane >> 4) * 4 + r;
            #pragma unroll
            for (int fn = 0; fn < 2; ++fn) {
                int col = n0 + wn + fn * 16 + (lane & 15);
                float g = accg[fm][fn][r];
                float u = accu[fm][fn][r];
                H[(size_t)row * IDIM + col] = bf(g / (1.f + expf(-g)) * u);
            }
        }
}

// ---------------- GEMM2: H @ Wd^T -> Y fp32 (no atomics) ----------------
// R7 structure + balanced chunking + 4-bit B swizzle.
__global__ __launch_bounds__(256, 3) void gemm2_kernel(
    const short* __restrict__ H, const float* __restrict__ DP,
    const int* __restrict__ cnt, float* __restrict__ Yf)
{
    int bid = balanced_bid(cnt, 8);
    if (bid < 0) return;
    int e, mt, nt;
    if (!decode_wmajor(cnt, bid, 8, e, mt, nt)) return;
    int m0 = mt * 128, n0 = nt * 128;

    __shared__ short As[128 * 64];   // 16 KB
    __shared__ float Bs[128 * 64];   // 32 KB

    int tid = threadIdx.x, lane = tid & 63, wv = tid >> 6;
    int wm = (wv >> 1) * 64, wn = (wv & 1) * 64;

    f32x4 acc[4][4] = {};

    int swcolA = ((lane & 7) ^ (lane >> 3)) * 8;
    const float* dbase = DP + ((size_t)e * DIM + n0) * IDIM;

    auto stage = [&](int k0) {
        #pragma unroll
        for (int j = 0; j < 4; ++j) {            // A: 4 calls/wave, 8 rows/call
            int ch = wv * 4 + j;
            glds16(H + (size_t)(m0 + ch * 8 + (lane >> 3)) * IDIM + k0 + swcolA, &As[ch * 512]);
        }
        #pragma unroll
        for (int j = 0; j < 8; ++j) {            // B: 8 calls/wave, 4 rows/call (128 rows)
            int ch = wv * 8 + j;
            int r  = ch * 4 + (lane >> 4);
            int sc = ((lane & 15) ^ (r & 15)) << 2;
            glds16(dbase + (size_t)r * IDIM + k0 + sc, &Bs[ch * 256]);
        }
    };

    int swrA = (lane & 7) << 3;
    int rx   = lane & 15;
    for (int it = 0; it < IDIM / 64; ++it) {
        stage(it * 64);
        __syncthreads();
        #pragma unroll
        for (int kk = 0; kk < 64; kk += 32) {
            int kiA = (kk + (lane >> 4) * 8) ^ swrA;
            sh8 af[4], bq[4];
            #pragma unroll
            for (int fm = 0; fm < 4; ++fm)
                af[fm] = *reinterpret_cast<const sh8*>(&As[(wm + fm * 16 + (lane & 15)) * 64 + kiA]);
            int c0 = (kk >> 2) + (lane >> 4) * 2;
            #pragma unroll
            for (int fn = 0; fn < 4; ++fn) {
                int R = wn + fn * 16 + (lane & 15);
                const float* bs = &Bs[R * 64];
                f32x4 lo = *reinterpret_cast<const f32x4*>(&bs[(c0       ^ rx) << 2]);
                f32x4 hi = *reinterpret_cast<const f32x4*>(&bs[((c0 + 1) ^ rx) << 2]);
                bq[fn] = cvt8(lo, hi);
            }
            #pragma unroll
            for (int fm = 0; fm < 4; ++fm)
                #pragma unroll
                for (int fn = 0; fn < 4; ++fn)
                    acc[fm][fn] = __builtin_amdgcn_mfma_f32_16x16x32_bf16(af[fm], bq[fn], acc[fm][fn], 0, 0, 0);
        }
        __syncthreads();
    }

    #pragma unroll
    for (int fm = 0; fm < 4; ++fm)
        #pragma unroll
        for (int r = 0; r < 4; ++r) {
            int row = m0 + wm + fm * 16 + (lane >> 4) * 4 + r;
            #pragma unroll
            for (int fn = 0; fn < 4; ++fn) {
                int col = n0 + wn + fn * 16 + (lane & 15);
                Yf[(size_t)row * DIM + col] = acc[fm][fn][r];
            }
        }
}

// ---------------- Combine: out[t] = sum_k w_k * Y[row(t,k)] ----------------
__global__ __launch_bounds__(256) void combine_kernel(
    const float* __restrict__ Yf, const int* __restrict__ cnt,
    const int* __restrict__ topk_idx, const float* __restrict__ topk_w,
    const int* __restrict__ posmap, float* __restrict__ out)
{
    int t = blockIdx.x;
    int d = threadIdx.x * 4;
    int es[TOPK], rows[TOPK];
    #pragma unroll
    for (int k = 0; k < TOPK; ++k) es[k] = topk_idx[t * TOPK + k];
    int p = 0;
    #pragma unroll
    for (int i = 0; i < NEXP; ++i) {
        #pragma unroll
        for (int k = 0; k < TOPK; ++k)
            if (es[k] == i) rows[k] = p + posmap[t * TOPK + k];
        p += ((cnt[i] + 127) >> 7) << 7;
    }
    float4 acc = make_float4(0.f, 0.f, 0.f, 0.f);
    #pragma unroll
    for (int k = 0; k < TOPK; ++k) {
        float w = topk_w[t * TOPK + k];
        float4 y = *reinterpret_cast<const float4*>(Yf + (size_t)rows[k] * DIM + d);
        acc.x += w * y.x; acc.y += w * y.y; acc.z += w * y.z; acc.w += w * y.w;
    }
    *reinterpret_cast<float4*>(out + (size_t)t * DIM + d) = acc;
}

// ---------------- launch ----------------
extern "C" void kernel_launch(void* const* d_in, const int* in_sizes, int n_in,
                              void* d_out, int out_size, void* d_ws, size_t ws_size,
                              hipStream_t stream)
{
    const float* X    = (const float*)d_in[0];
    const float* GW   = (const float*)d_in[1];
    const float* GUP  = (const float*)d_in[2];
    const float* DP   = (const float*)d_in[3];
    const float* BIAS = (const float*)d_in[4];
    float* out = (float*)d_out;

    char* ws = (char*)d_ws;
    int*   cnt      = (int*)ws;                       // 128 B
    int*   topk_idx = (int*)(ws + (4u   << 10));      // 64 KB
    float* topk_w   = (float*)(ws + (68u  << 10));    // 64 KB
    int*   posmap   = (int*)(ws + (132u << 10));      // 64 KB
    int*   tlist_c  = (int*)(ws + (196u << 10));      // 512 KB

    constexpr size_t OFF_H  = 2ull << 20;
    constexpr size_t SZ_BF  = (size_t)RPAD * IDIM * 2;   // 40 MB
    constexpr size_t OFF_XG = OFF_H + SZ_BF;             // 42 MB
    constexpr size_t OFF_YF = OFF_XG + SZ_BF;            // 82 MB

    short* H  = (short*)(ws + OFF_H);
    short* Xg = (short*)(ws + OFF_XG);
    float* Yf = (float*)(ws + OFF_YF);

    (void)hipMemsetAsync(cnt, 0, 128, stream);

    router_kernel<<<T_TOK / 4, 256, 0, stream>>>(X, GW, BIAS, topk_idx, topk_w,
                                                 cnt, tlist_c, posmap);
    gather_kernel<<<RPAD / 4, 256, 0, stream>>>(X, cnt, tlist_c, Xg);

    gemm1_kernel<<<MAXT * 16, 256, 0, stream>>>(Xg, GUP, cnt, H);      // 2560 hw blocks
    gemm2_kernel<<<MAXT * 8,  256, 0, stream>>>(H, DP, cnt, Yf);       // 1280 hw blocks

    combine_kernel<<<T_TOK, 256, 0, stream>>>(Yf, cnt, topk_idx, topk_w, posmap, out);
}

// Round 10
// 328.965 us; speedup vs baseline: 1.2498x; 1.0011x over previous
//
#include <hip/hip_runtime.h>
#include <hip/hip_bf16.h>
#include <cstdint>
#include <cstddef>

#define T_TOK 4096
#define DIM   1024
#define IDIM  1024
#define NEXP  32
#define TOPK  4
#define MAXT  160            // max 128-row m-tiles (128 full + <=32 pad)
#define RPAD  (MAXT*128)     // 20480 padded rows max

typedef short sh8   __attribute__((ext_vector_type(8)));
typedef float f32x4 __attribute__((ext_vector_type(4)));

__device__ __forceinline__ short bf(float f) {
    union { float f; uint32_t u; } v; v.f = f;
    uint32_t r = (v.u + 0x7FFFu + ((v.u >> 16) & 1u)) >> 16;   // RNE
    return (short)r;
}
__device__ __forceinline__ sh8 pack8(float4 a, float4 b) {
    sh8 r;
    r[0]=bf(a.x); r[1]=bf(a.y); r[2]=bf(a.z); r[3]=bf(a.w);
    r[4]=bf(b.x); r[5]=bf(b.y); r[6]=bf(b.z); r[7]=bf(b.w);
    return r;
}
// fp32 pair -> packed 2x bf16 (RNE), gfx950
__device__ __forceinline__ uint32_t cvtpk(float lo, float hi) {
    uint32_t r;
    asm("v_cvt_pk_bf16_f32 %0, %1, %2" : "=v"(r) : "v"(lo), "v"(hi));
    return r;
}
__device__ __forceinline__ sh8 cvt8(f32x4 a, f32x4 b) {
    union { uint32_t u[4]; sh8 s; } v;
    v.u[0] = cvtpk(a[0], a[1]); v.u[1] = cvtpk(a[2], a[3]);
    v.u[2] = cvtpk(b[0], b[1]); v.u[3] = cvtpk(b[2], b[3]);
    return v.s;
}
__device__ __forceinline__ void glds16(const void* g, const void* l) {
    __builtin_amdgcn_global_load_lds((const __attribute__((address_space(1))) void*)g,
                                     (__attribute__((address_space(3))) void*)l, 16, 0, 0);
}

// row-tile -> expert map (gather): which expert owns m-tile `mt`
__device__ __forceinline__ int tile_expert(const int* __restrict__ cnt, int mt, int& tile_start) {
    int s = 0, e = -1, ts = 0;
    #pragma unroll
    for (int i = 0; i < NEXP; ++i) {
        int t = (cnt[i] + 127) >> 7;
        if (mt >= s && mt < s + t) { e = i; ts = s; }
        s += t;
    }
    tile_start = ts;
    return e;
}

// Balanced bijective XCD chunking (m204): hw block -> logical bid such that each
// XCD gets a CONTIGUOUS logical chunk of ~total/8 (slab L2-affinity preserved)
// and idle blocks spread evenly across XCDs (fixes the idle-XCD-7 tail).
__device__ __forceinline__ int balanced_bid(const int* __restrict__ cnt, int ntsz) {
    int tb = 0;
    #pragma unroll
    for (int i = 0; i < NEXP; ++i) tb += (cnt[i] + 127) >> 7;
    int total = tb * ntsz;
    int q = total >> 3, r = total & 7;
    int xcd = (int)blockIdx.x & 7, pos = (int)blockIdx.x >> 3;
    int cap = q + (xcd < r ? 1 : 0);
    if (pos >= cap) return -1;
    return (xcd < r ? xcd * (q + 1) : r * (q + 1) + (xcd - r) * q) + pos;
}

// WEIGHT-MAJOR block decode: blocks sharing a weight slab (e,nt) are consecutive.
__device__ __forceinline__ bool decode_wmajor(const int* __restrict__ cnt, int bid, int ntsz,
                                              int& e, int& mt, int& nt) {
    int base = 0, tacc = 0, fe = -1, floc = 0, fts = 0, fntl = 1;
    #pragma unroll
    for (int i = 0; i < NEXP; ++i) {
        int ntl = (cnt[i] + 127) >> 7;
        int sz  = ntsz * ntl;
        if (bid >= base && bid < base + sz) { fe = i; floc = bid - base; fts = tacc; fntl = ntl; }
        base += sz; tacc += ntl;
    }
    if (fe < 0) return false;
    e  = fe;
    nt = floc / fntl;
    mt = fts + (floc % fntl);
    return true;
}

// ---------------- Router: one wave per token, fp32 ----------------
__global__ __launch_bounds__(256) void router_kernel(
    const float* __restrict__ X, const float* __restrict__ GW,
    const float* __restrict__ bias, int* __restrict__ topk_idx,
    float* __restrict__ topk_w, int* __restrict__ cnt,
    int* __restrict__ tlist_c, int* __restrict__ posmap)
{
    int wid  = threadIdx.x >> 6;
    int lane = threadIdx.x & 63;
    int t = blockIdx.x * 4 + wid;

    float4 h[4];
    const float4* xr = reinterpret_cast<const float4*>(X + (size_t)t * DIM);
    #pragma unroll
    for (int c = 0; c < 4; ++c) h[c] = xr[lane + 64 * c];

    float myscore = 0.f;
    for (int e = 0; e < NEXP; ++e) {
        const float4* gr = reinterpret_cast<const float4*>(GW + (size_t)e * DIM);
        float p = 0.f;
        #pragma unroll
        for (int c = 0; c < 4; ++c) {
            float4 g = gr[lane + 64 * c];
            p += h[c].x * g.x + h[c].y * g.y + h[c].z * g.z + h[c].w * g.w;
        }
        #pragma unroll
        for (int o = 32; o; o >>= 1) p += __shfl_xor(p, o);
        if (lane == e) myscore = p;
    }
    float rw = 1.f / (1.f + expf(-myscore));
    float sel = (lane < NEXP) ? rw + bias[lane] : -1e30f;

    float wsum = 0.f;
    int   oi = 0; float ow = 0.f;
    #pragma unroll
    for (int k = 0; k < TOPK; ++k) {
        float v = sel;
        int   idx = (lane < NEXP) ? lane : 9999;
        #pragma unroll
        for (int o = 32; o; o >>= 1) {
            float v2 = __shfl_xor(v, o);
            int   i2 = __shfl_xor(idx, o);
            if (v2 > v || (v2 == v && i2 < idx)) { v = v2; idx = i2; }
        }
        float wk = __shfl(rw, idx);
        wsum += wk;
        if (lane == k)   { oi = idx; ow = wk; }
        if (lane == idx) sel = -1e30f;
    }
    if (lane < TOPK) {
        int gid = t * TOPK + lane;
        topk_idx[gid] = oi;
        topk_w  [gid] = ow / (wsum + 1e-6f);
        int pos = atomicAdd(&cnt[oi], 1);   // order-nondeterministic; consumption is order-invariant
        tlist_c[oi * T_TOK + pos] = t;
        posmap[gid] = pos;
    }
}

// ---------------- Gather: build padded Xg bf16 ----------------
__global__ __launch_bounds__(256) void gather_kernel(
    const float* __restrict__ X, const int* __restrict__ cnt,
    const int* __restrict__ tlist_c, short* __restrict__ Xg)
{
    int wid = threadIdx.x >> 6, lane = threadIdx.x & 63;
    int r = blockIdx.x * 4 + wid;
    int ts;
    int e = tile_expert(cnt, r >> 7, ts);
    if (e < 0) return;
    int li = r - (ts << 7);
    bool real = li < cnt[e];
    int t = real ? tlist_c[e * T_TOK + li] : 0;
    const float4* src = reinterpret_cast<const float4*>(X + (size_t)t * DIM);
    sh8* dst = reinterpret_cast<sh8*>(Xg + (size_t)r * DIM);
    float4 z = make_float4(0.f, 0.f, 0.f, 0.f);
    #pragma unroll
    for (int it = 0; it < 2; ++it) {
        int si = it * 64 + lane;
        float4 a = real ? src[2 * si]     : z;
        float4 b = real ? src[2 * si + 1] : z;
        dst[si] = pack8(a, b);
    }
}

// ---------------- GEMM1: Xg @ Wgu^T (g,u fused), silu, H bf16 ----------------
// R7 structure (proven best): A bf16 glds16; B fp32 glds16 direct to LDS,
// cvt_pk at fragment read. Changes vs R7: balanced XCD chunking; B swizzle
// key widened to 4 bits (r&15) on BOTH glds source and read index.
__global__ __launch_bounds__(256, 3) void gemm1_kernel(
    const short* __restrict__ Xg, const float* __restrict__ GUP,
    const int* __restrict__ cnt, short* __restrict__ H)
{
    int bid = balanced_bid(cnt, 16);
    if (bid < 0) return;
    int e, mt, nt;
    if (!decode_wmajor(cnt, bid, 16, e, mt, nt)) return;
    int m0 = mt * 128, n0 = nt * 64;

    __shared__ short As[128 * 64];   // 16 KB bf16
    __shared__ float Bg[64 * 64];    // 16 KB fp32
    __shared__ float Bu[64 * 64];    // 16 KB fp32

    int tid = threadIdx.x, lane = tid & 63, wv = tid >> 6;
    int wm = (wv >> 1) * 64, wn = (wv & 1) * 32;

    f32x4 accg[4][2] = {};
    f32x4 accu[4][2] = {};

    int swcolA = ((lane & 7) ^ (lane >> 3)) * 8;   // A pre-swizzled source col (bf16 elems)
    const float* gbase = GUP + ((size_t)e * 2 * IDIM + n0) * DIM;
    const float* ubase = gbase + (size_t)IDIM * DIM;

    auto stage = [&](int k0) {
        #pragma unroll
        for (int j = 0; j < 4; ++j) {            // A: 4 calls/wave, 8 rows/call
            int ch = wv * 4 + j;
            glds16(Xg + (size_t)(m0 + ch * 8 + (lane >> 3)) * DIM + k0 + swcolA, &As[ch * 512]);
        }
        #pragma unroll
        for (int j = 0; j < 4; ++j) {            // Bg/Bu: 4 calls/wave each, 4 rows/call
            int ch = wv * 4 + j;
            int r  = ch * 4 + (lane >> 4);
            int sc = ((lane & 15) ^ (r & 15)) << 2;   // 4-bit involution over 16 chunks/row
            glds16(gbase + (size_t)r * DIM + k0 + sc, &Bg[ch * 256]);
            glds16(ubase + (size_t)r * DIM + k0 + sc, &Bu[ch * 256]);
        }
    };

    int swrA = (lane & 7) << 3;
    int rx   = lane & 15;                         // R&15 for B-frag rows (R = wn+fn*16+(lane&15))
    for (int it = 0; it < DIM / 64; ++it) {
        stage(it * 64);
        __syncthreads();                          // vmcnt(0) drained here by compiler
        #pragma unroll
        for (int kk = 0; kk < 64; kk += 32) {
            int kiA = (kk + (lane >> 4) * 8) ^ swrA;
            sh8 af[4], gf[2], uf[2];
            #pragma unroll
            for (int fm = 0; fm < 4; ++fm)
                af[fm] = *reinterpret_cast<const sh8*>(&As[(wm + fm * 16 + (lane & 15)) * 64 + kiA]);
            int c0 = (kk >> 2) + (lane >> 4) * 2;         // 16B-chunk index within row (even)
            #pragma unroll
            for (int fn = 0; fn < 2; ++fn) {
                int R = wn + fn * 16 + (lane & 15);
                const float* bg = &Bg[R * 64];
                f32x4 lo = *reinterpret_cast<const f32x4*>(&bg[(c0       ^ rx) << 2]);
                f32x4 hi = *reinterpret_cast<const f32x4*>(&bg[((c0 + 1) ^ rx) << 2]);
                gf[fn] = cvt8(lo, hi);
                const float* bu = &Bu[R * 64];
                lo = *reinterpret_cast<const f32x4*>(&bu[(c0       ^ rx) << 2]);
                hi = *reinterpret_cast<const f32x4*>(&bu[((c0 + 1) ^ rx) << 2]);
                uf[fn] = cvt8(lo, hi);
            }
            #pragma unroll
            for (int fm = 0; fm < 4; ++fm)
                #pragma unroll
                for (int fn = 0; fn < 2; ++fn) {
                    accg[fm][fn] = __builtin_amdgcn_mfma_f32_16x16x32_bf16(af[fm], gf[fn], accg[fm][fn], 0, 0, 0);
                    accu[fm][fn] = __builtin_amdgcn_mfma_f32_16x16x32_bf16(af[fm], uf[fn], accu[fm][fn], 0, 0, 0);
                }
        }
        __syncthreads();
    }

    #pragma unroll
    for (int fm = 0; fm < 4; ++fm)
        #pragma unroll
        for (int r = 0; r < 4; ++r) {
            int row = m0 + wm + fm * 16 + (lane >> 4) * 4 + r;
            #pragma unroll
            for (int fn = 0; fn < 2; ++fn) {
                int col = n0 + wn + fn * 16 + (lane & 15);
                float g = accg[fm][fn][r];
                float u = accu[fm][fn][r];
                H[(size_t)row * IDIM + col] = bf(g / (1.f + expf(-g)) * u);
            }
        }
}

// ---------------- GEMM2: H @ Wd^T -> Y fp32 (no atomics) ----------------
// R7 structure + balanced chunking + 4-bit B swizzle.
__global__ __launch_bounds__(256, 3) void gemm2_kernel(
    const short* __restrict__ H, const float* __restrict__ DP,
    const int* __restrict__ cnt, float* __restrict__ Yf)
{
    int bid = balanced_bid(cnt, 8);
    if (bid < 0) return;
    int e, mt, nt;
    if (!decode_wmajor(cnt, bid, 8, e, mt, nt)) return;
    int m0 = mt * 128, n0 = nt * 128;

    __shared__ short As[128 * 64];   // 16 KB
    __shared__ float Bs[128 * 64];   // 32 KB

    int tid = threadIdx.x, lane = tid & 63, wv = tid >> 6;
    int wm = (wv >> 1) * 64, wn = (wv & 1) * 64;

    f32x4 acc[4][4] = {};

    int swcolA = ((lane & 7) ^ (lane >> 3)) * 8;
    const float* dbase = DP + ((size_t)e * DIM + n0) * IDIM;

    auto stage = [&](int k0) {
        #pragma unroll
        for (int j = 0; j < 4; ++j) {            // A: 4 calls/wave, 8 rows/call
            int ch = wv * 4 + j;
            glds16(H + (size_t)(m0 + ch * 8 + (lane >> 3)) * IDIM + k0 + swcolA, &As[ch * 512]);
        }
        #pragma unroll
        for (int j = 0; j < 8; ++j) {            // B: 8 calls/wave, 4 rows/call (128 rows)
            int ch = wv * 8 + j;
            int r  = ch * 4 + (lane >> 4);
            int sc = ((lane & 15) ^ (r & 15)) << 2;
            glds16(dbase + (size_t)r * IDIM + k0 + sc, &Bs[ch * 256]);
        }
    };

    int swrA = (lane & 7) << 3;
    int rx   = lane & 15;
    for (int it = 0; it < IDIM / 64; ++it) {
        stage(it * 64);
        __syncthreads();
        #pragma unroll
        for (int kk = 0; kk < 64; kk += 32) {
            int kiA = (kk + (lane >> 4) * 8) ^ swrA;
            sh8 af[4], bq[4];
            #pragma unroll
            for (int fm = 0; fm < 4; ++fm)
                af[fm] = *reinterpret_cast<const sh8*>(&As[(wm + fm * 16 + (lane & 15)) * 64 + kiA]);
            int c0 = (kk >> 2) + (lane >> 4) * 2;
            #pragma unroll
            for (int fn = 0; fn < 4; ++fn) {
                int R = wn + fn * 16 + (lane & 15);
                const float* bs = &Bs[R * 64];
                f32x4 lo = *reinterpret_cast<const f32x4*>(&bs[(c0       ^ rx) << 2]);
                f32x4 hi = *reinterpret_cast<const f32x4*>(&bs[((c0 + 1) ^ rx) << 2]);
                bq[fn] = cvt8(lo, hi);
            }
            #pragma unroll
            for (int fm = 0; fm < 4; ++fm)
                #pragma unroll
                for (int fn = 0; fn < 4; ++fn)
                    acc[fm][fn] = __builtin_amdgcn_mfma_f32_16x16x32_bf16(af[fm], bq[fn], acc[fm][fn], 0, 0, 0);
        }
        __syncthreads();
    }

    #pragma unroll
    for (int fm = 0; fm < 4; ++fm)
        #pragma unroll
        for (int r = 0; r < 4; ++r) {
            int row = m0 + wm + fm * 16 + (lane >> 4) * 4 + r;
            #pragma unroll
            for (int fn = 0; fn < 4; ++fn) {
                int col = n0 + wn + fn * 16 + (lane & 15);
                Yf[(size_t)row * DIM + col] = acc[fm][fn][r];
            }
        }
}

// ---------------- Combine: out[t] = sum_k w_k * Y[row(t,k)] ----------------
__global__ __launch_bounds__(256) void combine_kernel(
    const float* __restrict__ Yf, const int* __restrict__ cnt,
    const int* __restrict__ topk_idx, const float* __restrict__ topk_w,
    const int* __restrict__ posmap, float* __restrict__ out)
{
    int t = blockIdx.x;
    int d = threadIdx.x * 4;
    int es[TOPK], rows[TOPK];
    #pragma unroll
    for (int k = 0; k < TOPK; ++k) es[k] = topk_idx[t * TOPK + k];
    int p = 0;
    #pragma unroll
    for (int i = 0; i < NEXP; ++i) {
        #pragma unroll
        for (int k = 0; k < TOPK; ++k)
            if (es[k] == i) rows[k] = p + posmap[t * TOPK + k];
        p += ((cnt[i] + 127) >> 7) << 7;
    }
    float4 acc = make_float4(0.f, 0.f, 0.f, 0.f);
    #pragma unroll
    for (int k = 0; k < TOPK; ++k) {
        float w = topk_w[t * TOPK + k];
        float4 y = *reinterpret_cast<const float4*>(Yf + (size_t)rows[k] * DIM + d);
        acc.x += w * y.x; acc.y += w * y.y; acc.z += w * y.z; acc.w += w * y.w;
    }
    *reinterpret_cast<float4*>(out + (size_t)t * DIM + d) = acc;
}

// ---------------- launch ----------------
extern "C" void kernel_launch(void* const* d_in, const int* in_sizes, int n_in,
                              void* d_out, int out_size, void* d_ws, size_t ws_size,
                              hipStream_t stream)
{
    const float* X    = (const float*)d_in[0];
    const float* GW   = (const float*)d_in[1];
    const float* GUP  = (const float*)d_in[2];
    const float* DP   = (const float*)d_in[3];
    const float* BIAS = (const float*)d_in[4];
    float* out = (float*)d_out;

    char* ws = (char*)d_ws;
    int*   cnt      = (int*)ws;                       // 128 B
    int*   topk_idx = (int*)(ws + (4u   << 10));      // 64 KB
    float* topk_w   = (float*)(ws + (68u  << 10));    // 64 KB
    int*   posmap   = (int*)(ws + (132u << 10));      // 64 KB
    int*   tlist_c  = (int*)(ws + (196u << 10));      // 512 KB

    constexpr size_t OFF_H  = 2ull << 20;
    constexpr size_t SZ_BF  = (size_t)RPAD * IDIM * 2;   // 40 MB
    constexpr size_t OFF_XG = OFF_H + SZ_BF;             // 42 MB
    constexpr size_t OFF_YF = OFF_XG + SZ_BF;            // 82 MB

    short* H  = (short*)(ws + OFF_H);
    short* Xg = (short*)(ws + OFF_XG);
    float* Yf = (float*)(ws + OFF_YF);

    (void)hipMemsetAsync(cnt, 0, 128, stream);

    router_kernel<<<T_TOK / 4, 256, 0, stream>>>(X, GW, BIAS, topk_idx, topk_w,
                                                 cnt, tlist_c, posmap);
    gather_kernel<<<RPAD / 4, 256, 0, stream>>>(X, cnt, tlist_c, Xg);

    gemm1_kernel<<<MAXT * 16, 256, 0, stream>>>(Xg, GUP, cnt, H);      // 2560 hw blocks
    gemm2_kernel<<<MAXT * 8,  256, 0, stream>>>(H, DP, cnt, Yf);       // 1280 hw blocks

    combine_kernel<<<T_TOK, 256, 0, stream>>>(Yf, cnt, topk_idx, topk_w, posmap, out);
}

// Round 11
// 328.927 us; speedup vs baseline: 1.2499x; 1.0001x over previous
//
#include <hip/hip_runtime.h>
#include <hip/hip_bf16.h>
#include <cstdint>
#include <cstddef>

#define T_TOK 4096
#define DIM   1024
#define IDIM  1024
#define NEXP  32
#define TOPK  4
#define MAXT  160            // max 128-row m-tiles (128 full + <=32 pad)
#define RPAD  (MAXT*128)     // 20480 padded rows max

typedef short sh8   __attribute__((ext_vector_type(8)));
typedef float f32x4 __attribute__((ext_vector_type(4)));

__device__ __forceinline__ short bf(float f) {
    union { float f; uint32_t u; } v; v.f = f;
    uint32_t r = (v.u + 0x7FFFu + ((v.u >> 16) & 1u)) >> 16;   // RNE
    return (short)r;
}
__device__ __forceinline__ sh8 pack8(float4 a, float4 b) {
    sh8 r;
    r[0]=bf(a.x); r[1]=bf(a.y); r[2]=bf(a.z); r[3]=bf(a.w);
    r[4]=bf(b.x); r[5]=bf(b.y); r[6]=bf(b.z); r[7]=bf(b.w);
    return r;
}
// fp32 pair -> packed 2x bf16 (RNE), gfx950
__device__ __forceinline__ uint32_t cvtpk(float lo, float hi) {
    uint32_t r;
    asm("v_cvt_pk_bf16_f32 %0, %1, %2" : "=v"(r) : "v"(lo), "v"(hi));
    return r;
}
__device__ __forceinline__ sh8 cvt8(f32x4 a, f32x4 b) {
    union { uint32_t u[4]; sh8 s; } v;
    v.u[0] = cvtpk(a[0], a[1]); v.u[1] = cvtpk(a[2], a[3]);
    v.u[2] = cvtpk(b[0], b[1]); v.u[3] = cvtpk(b[2], b[3]);
    return v.s;
}
__device__ __forceinline__ void glds16(const void* g, const void* l) {
    __builtin_amdgcn_global_load_lds((const __attribute__((address_space(1))) void*)g,
                                     (__attribute__((address_space(3))) void*)l, 16, 0, 0);
}

// row-tile -> expert map (gather): which expert owns m-tile `mt`
__device__ __forceinline__ int tile_expert(const int* __restrict__ cnt, int mt, int& tile_start) {
    int s = 0, e = -1, ts = 0;
    #pragma unroll
    for (int i = 0; i < NEXP; ++i) {
        int t = (cnt[i] + 127) >> 7;
        if (mt >= s && mt < s + t) { e = i; ts = s; }
        s += t;
    }
    tile_start = ts;
    return e;
}

// Balanced bijective XCD chunking (m204): hw block -> logical bid such that each
// XCD gets a CONTIGUOUS logical chunk of ~total/8 (slab L2-affinity preserved)
// and idle blocks spread evenly across XCDs (fixes the idle-XCD-7 tail).
__device__ __forceinline__ int balanced_bid(const int* __restrict__ cnt, int ntsz) {
    int tb = 0;
    #pragma unroll
    for (int i = 0; i < NEXP; ++i) tb += (cnt[i] + 127) >> 7;
    int total = tb * ntsz;
    int q = total >> 3, r = total & 7;
    int xcd = (int)blockIdx.x & 7, pos = (int)blockIdx.x >> 3;
    int cap = q + (xcd < r ? 1 : 0);
    if (pos >= cap) return -1;
    return (xcd < r ? xcd * (q + 1) : r * (q + 1) + (xcd - r) * q) + pos;
}

// WEIGHT-MAJOR block decode: blocks sharing a weight slab (e,nt) are consecutive.
__device__ __forceinline__ bool decode_wmajor(const int* __restrict__ cnt, int bid, int ntsz,
                                              int& e, int& mt, int& nt) {
    int base = 0, tacc = 0, fe = -1, floc = 0, fts = 0, fntl = 1;
    #pragma unroll
    for (int i = 0; i < NEXP; ++i) {
        int ntl = (cnt[i] + 127) >> 7;
        int sz  = ntsz * ntl;
        if (bid >= base && bid < base + sz) { fe = i; floc = bid - base; fts = tacc; fntl = ntl; }
        base += sz; tacc += ntl;
    }
    if (fe < 0) return false;
    e  = fe;
    nt = floc / fntl;
    mt = fts + (floc % fntl);
    return true;
}

// ---------------- Router: one wave per token, fp32 ----------------
__global__ __launch_bounds__(256) void router_kernel(
    const float* __restrict__ X, const float* __restrict__ GW,
    const float* __restrict__ bias, int* __restrict__ topk_idx,
    float* __restrict__ topk_w, int* __restrict__ cnt,
    int* __restrict__ tlist_c, int* __restrict__ posmap)
{
    int wid  = threadIdx.x >> 6;
    int lane = threadIdx.x & 63;
    int t = blockIdx.x * 4 + wid;

    float4 h[4];
    const float4* xr = reinterpret_cast<const float4*>(X + (size_t)t * DIM);
    #pragma unroll
    for (int c = 0; c < 4; ++c) h[c] = xr[lane + 64 * c];

    float myscore = 0.f;
    for (int e = 0; e < NEXP; ++e) {
        const float4* gr = reinterpret_cast<const float4*>(GW + (size_t)e * DIM);
        float p = 0.f;
        #pragma unroll
        for (int c = 0; c < 4; ++c) {
            float4 g = gr[lane + 64 * c];
            p += h[c].x * g.x + h[c].y * g.y + h[c].z * g.z + h[c].w * g.w;
        }
        #pragma unroll
        for (int o = 32; o; o >>= 1) p += __shfl_xor(p, o);
        if (lane == e) myscore = p;
    }
    float rw = 1.f / (1.f + expf(-myscore));
    float sel = (lane < NEXP) ? rw + bias[lane] : -1e30f;

    float wsum = 0.f;
    int   oi = 0; float ow = 0.f;
    #pragma unroll
    for (int k = 0; k < TOPK; ++k) {
        float v = sel;
        int   idx = (lane < NEXP) ? lane : 9999;
        #pragma unroll
        for (int o = 32; o; o >>= 1) {
            float v2 = __shfl_xor(v, o);
            int   i2 = __shfl_xor(idx, o);
            if (v2 > v || (v2 == v && i2 < idx)) { v = v2; idx = i2; }
        }
        float wk = __shfl(rw, idx);
        wsum += wk;
        if (lane == k)   { oi = idx; ow = wk; }
        if (lane == idx) sel = -1e30f;
    }
    if (lane < TOPK) {
        int gid = t * TOPK + lane;
        topk_idx[gid] = oi;
        topk_w  [gid] = ow / (wsum + 1e-6f);
        int pos = atomicAdd(&cnt[oi], 1);   // order-nondeterministic; consumption is order-invariant
        tlist_c[oi * T_TOK + pos] = t;
        posmap[gid] = pos;
    }
}

// ---------------- Gather: build padded Xg bf16 ----------------
__global__ __launch_bounds__(256) void gather_kernel(
    const float* __restrict__ X, const int* __restrict__ cnt,
    const int* __restrict__ tlist_c, short* __restrict__ Xg)
{
    int wid = threadIdx.x >> 6, lane = threadIdx.x & 63;
    int r = blockIdx.x * 4 + wid;
    int ts;
    int e = tile_expert(cnt, r >> 7, ts);
    if (e < 0) return;
    int li = r - (ts << 7);
    bool real = li < cnt[e];
    int t = real ? tlist_c[e * T_TOK + li] : 0;
    const float4* src = reinterpret_cast<const float4*>(X + (size_t)t * DIM);
    sh8* dst = reinterpret_cast<sh8*>(Xg + (size_t)r * DIM);
    float4 z = make_float4(0.f, 0.f, 0.f, 0.f);
    #pragma unroll
    for (int it = 0; it < 2; ++it) {
        int si = it * 64 + lane;
        float4 a = real ? src[2 * si]     : z;
        float4 b = real ? src[2 * si + 1] : z;
        dst[si] = pack8(a, b);
    }
}

// ---------------- GEMM1: Xg @ Wgu^T (g,u fused), silu, H bf16 ----------------
// R7 structure (proven best): A bf16 glds16; B fp32 glds16 direct to LDS,
// cvt_pk at fragment read. Changes vs R7: balanced XCD chunking; B swizzle
// key widened to 4 bits (r&15) on BOTH glds source and read index.
__global__ __launch_bounds__(256, 3) void gemm1_kernel(
    const short* __restrict__ Xg, const float* __restrict__ GUP,
    const int* __restrict__ cnt, short* __restrict__ H)
{
    int bid = balanced_bid(cnt, 16);
    if (bid < 0) return;
    int e, mt, nt;
    if (!decode_wmajor(cnt, bid, 16, e, mt, nt)) return;
    int m0 = mt * 128, n0 = nt * 64;

    __shared__ short As[128 * 64];   // 16 KB bf16
    __shared__ float Bg[64 * 64];    // 16 KB fp32
    __shared__ float Bu[64 * 64];    // 16 KB fp32

    int tid = threadIdx.x, lane = tid & 63, wv = tid >> 6;
    int wm = (wv >> 1) * 64, wn = (wv & 1) * 32;

    f32x4 accg[4][2] = {};
    f32x4 accu[4][2] = {};

    int swcolA = ((lane & 7) ^ (lane >> 3)) * 8;   // A pre-swizzled source col (bf16 elems)
    const float* gbase = GUP + ((size_t)e * 2 * IDIM + n0) * DIM;
    const float* ubase = gbase + (size_t)IDIM * DIM;

    auto stage = [&](int k0) {
        #pragma unroll
        for (int j = 0; j < 4; ++j) {            // A: 4 calls/wave, 8 rows/call
            int ch = wv * 4 + j;
            glds16(Xg + (size_t)(m0 + ch * 8 + (lane >> 3)) * DIM + k0 + swcolA, &As[ch * 512]);
        }
        #pragma unroll
        for (int j = 0; j < 4; ++j) {            // Bg/Bu: 4 calls/wave each, 4 rows/call
            int ch = wv * 4 + j;
            int r  = ch * 4 + (lane >> 4);
            int sc = ((lane & 15) ^ (r & 15)) << 2;   // 4-bit involution over 16 chunks/row
            glds16(gbase + (size_t)r * DIM + k0 + sc, &Bg[ch * 256]);
            glds16(ubase + (size_t)r * DIM + k0 + sc, &Bu[ch * 256]);
        }
    };

    int swrA = (lane & 7) << 3;
    int rx   = lane & 15;                         // R&15 for B-frag rows (R = wn+fn*16+(lane&15))
    for (int it = 0; it < DIM / 64; ++it) {
        stage(it * 64);
        __syncthreads();                          // vmcnt(0) drained here by compiler
        #pragma unroll
        for (int kk = 0; kk < 64; kk += 32) {
            int kiA = (kk + (lane >> 4) * 8) ^ swrA;
            sh8 af[4], gf[2], uf[2];
            #pragma unroll
            for (int fm = 0; fm < 4; ++fm)
                af[fm] = *reinterpret_cast<const sh8*>(&As[(wm + fm * 16 + (lane & 15)) * 64 + kiA]);
            int c0 = (kk >> 2) + (lane >> 4) * 2;         // 16B-chunk index within row (even)
            #pragma unroll
            for (int fn = 0; fn < 2; ++fn) {
                int R = wn + fn * 16 + (lane & 15);
                const float* bg = &Bg[R * 64];
                f32x4 lo = *reinterpret_cast<const f32x4*>(&bg[(c0       ^ rx) << 2]);
                f32x4 hi = *reinterpret_cast<const f32x4*>(&bg[((c0 + 1) ^ rx) << 2]);
                gf[fn] = cvt8(lo, hi);
                const float* bu = &Bu[R * 64];
                lo = *reinterpret_cast<const f32x4*>(&bu[(c0       ^ rx) << 2]);
                hi = *reinterpret_cast<const f32x4*>(&bu[((c0 + 1) ^ rx) << 2]);
                uf[fn] = cvt8(lo, hi);
            }
            #pragma unroll
            for (int fm = 0; fm < 4; ++fm)
                #pragma unroll
                for (int fn = 0; fn < 2; ++fn) {
                    accg[fm][fn] = __builtin_amdgcn_mfma_f32_16x16x32_bf16(af[fm], gf[fn], accg[fm][fn], 0, 0, 0);
                    accu[fm][fn] = __builtin_amdgcn_mfma_f32_16x16x32_bf16(af[fm], uf[fn], accu[fm][fn], 0, 0, 0);
                }
        }
        __syncthreads();
    }

    #pragma unroll
    for (int fm = 0; fm < 4; ++fm)
        #pragma unroll
        for (int r = 0; r < 4; ++r) {
            int row = m0 + wm + fm * 16 + (lane >> 4) * 4 + r;
            #pragma unroll
            for (int fn = 0; fn < 2; ++fn) {
                int col = n0 + wn + fn * 16 + (lane & 15);
                float g = accg[fm][fn][r];
                float u = accu[fm][fn][r];
                H[(size_t)row * IDIM + col] = bf(g / (1.f + expf(-g)) * u);
            }
        }
}

// ---------------- GEMM2: H @ Wd^T -> Y fp32 (no atomics) ----------------
// R7 structure + balanced chunking + 4-bit B swizzle.
__global__ __launch_bounds__(256, 3) void gemm2_kernel(
    const short* __restrict__ H, const float* __restrict__ DP,
    const int* __restrict__ cnt, float* __restrict__ Yf)
{
    int bid = balanced_bid(cnt, 8);
    if (bid < 0) return;
    int e, mt, nt;
    if (!decode_wmajor(cnt, bid, 8, e, mt, nt)) return;
    int m0 = mt * 128, n0 = nt * 128;

    __shared__ short As[128 * 64];   // 16 KB
    __shared__ float Bs[128 * 64];   // 32 KB

    int tid = threadIdx.x, lane = tid & 63, wv = tid >> 6;
    int wm = (wv >> 1) * 64, wn = (wv & 1) * 64;

    f32x4 acc[4][4] = {};

    int swcolA = ((lane & 7) ^ (lane >> 3)) * 8;
    const float* dbase = DP + ((size_t)e * DIM + n0) * IDIM;

    auto stage = [&](int k0) {
        #pragma unroll
        for (int j = 0; j < 4; ++j) {            // A: 4 calls/wave, 8 rows/call
            int ch = wv * 4 + j;
            glds16(H + (size_t)(m0 + ch * 8 + (lane >> 3)) * IDIM + k0 + swcolA, &As[ch * 512]);
        }
        #pragma unroll
        for (int j = 0; j < 8; ++j) {            // B: 8 calls/wave, 4 rows/call (128 rows)
            int ch = wv * 8 + j;
            int r  = ch * 4 + (lane >> 4);
            int sc = ((lane & 15) ^ (r & 15)) << 2;
            glds16(dbase + (size_t)r * IDIM + k0 + sc, &Bs[ch * 256]);
        }
    };

    int swrA = (lane & 7) << 3;
    int rx   = lane & 15;
    for (int it = 0; it < IDIM / 64; ++it) {
        stage(it * 64);
        __syncthreads();
        #pragma unroll
        for (int kk = 0; kk < 64; kk += 32) {
            int kiA = (kk + (lane >> 4) * 8) ^ swrA;
            sh8 af[4], bq[4];
            #pragma unroll
            for (int fm = 0; fm < 4; ++fm)
                af[fm] = *reinterpret_cast<const sh8*>(&As[(wm + fm * 16 + (lane & 15)) * 64 + kiA]);
            int c0 = (kk >> 2) + (lane >> 4) * 2;
            #pragma unroll
            for (int fn = 0; fn < 4; ++fn) {
                int R = wn + fn * 16 + (lane & 15);
                const float* bs = &Bs[R * 64];
                f32x4 lo = *reinterpret_cast<const f32x4*>(&bs[(c0       ^ rx) << 2]);
                f32x4 hi = *reinterpret_cast<const f32x4*>(&bs[((c0 + 1) ^ rx) << 2]);
                bq[fn] = cvt8(lo, hi);
            }
            #pragma unroll
            for (int fm = 0; fm < 4; ++fm)
                #pragma unroll
                for (int fn = 0; fn < 4; ++fn)
                    acc[fm][fn] = __builtin_amdgcn_mfma_f32_16x16x32_bf16(af[fm], bq[fn], acc[fm][fn], 0, 0, 0);
        }
        __syncthreads();
    }

    #pragma unroll
    for (int fm = 0; fm < 4; ++fm)
        #pragma unroll
        for (int r = 0; r < 4; ++r) {
            int row = m0 + wm + fm * 16 + (lane >> 4) * 4 + r;
            #pragma unroll
            for (int fn = 0; fn < 4; ++fn) {
                int col = n0 + wn + fn * 16 + (lane & 15);
                Yf[(size_t)row * DIM + col] = acc[fm][fn][r];
            }
        }
}

// ---------------- Combine: out[t] = sum_k w_k * Y[row(t,k)] ----------------
__global__ __launch_bounds__(256) void combine_kernel(
    const float* __restrict__ Yf, const int* __restrict__ cnt,
    const int* __restrict__ topk_idx, const float* __restrict__ topk_w,
    const int* __restrict__ posmap, float* __restrict__ out)
{
    int t = blockIdx.x;
    int d = threadIdx.x * 4;
    int es[TOPK], rows[TOPK];
    #pragma unroll
    for (int k = 0; k < TOPK; ++k) es[k] = topk_idx[t * TOPK + k];
    int p = 0;
    #pragma unroll
    for (int i = 0; i < NEXP; ++i) {
        #pragma unroll
        for (int k = 0; k < TOPK; ++k)
            if (es[k] == i) rows[k] = p + posmap[t * TOPK + k];
        p += ((cnt[i] + 127) >> 7) << 7;
    }
    float4 acc = make_float4(0.f, 0.f, 0.f, 0.f);
    #pragma unroll
    for (int k = 0; k < TOPK; ++k) {
        float w = topk_w[t * TOPK + k];
        float4 y = *reinterpret_cast<const float4*>(Yf + (size_t)rows[k] * DIM + d);
        acc.x += w * y.x; acc.y += w * y.y; acc.z += w * y.z; acc.w += w * y.w;
    }
    *reinterpret_cast<float4*>(out + (size_t)t * DIM + d) = acc;
}

// ---------------- launch ----------------
extern "C" void kernel_launch(void* const* d_in, const int* in_sizes, int n_in,
                              void* d_out, int out_size, void* d_ws, size_t ws_size,
                              hipStream_t stream)
{
    const float* X    = (const float*)d_in[0];
    const float* GW   = (const float*)d_in[1];
    const float* GUP  = (const float*)d_in[2];
    const float* DP   = (const float*)d_in[3];
    const float* BIAS = (const float*)d_in[4];
    float* out = (float*)d_out;

    char* ws = (char*)d_ws;
    int*   cnt      = (int*)ws;                       // 128 B
    int*   topk_idx = (int*)(ws + (4u   << 10));      // 64 KB
    float* topk_w   = (float*)(ws + (68u  << 10));    // 64 KB
    int*   posmap   = (int*)(ws + (132u << 10));      // 64 KB
    int*   tlist_c  = (int*)(ws + (196u << 10));      // 512 KB

    constexpr size_t OFF_H  = 2ull << 20;
    constexpr size_t SZ_BF  = (size_t)RPAD * IDIM * 2;   // 40 MB
    constexpr size_t OFF_XG = OFF_H + SZ_BF;             // 42 MB
    constexpr size_t OFF_YF = OFF_XG + SZ_BF;            // 82 MB

    short* H  = (short*)(ws + OFF_H);
    short* Xg = (short*)(ws + OFF_XG);
    float* Yf = (float*)(ws + OFF_YF);

    (void)hipMemsetAsync(cnt, 0, 128, stream);

    router_kernel<<<T_TOK / 4, 256, 0, stream>>>(X, GW, BIAS, topk_idx, topk_w,
                                                 cnt, tlist_c, posmap);
    gather_kernel<<<RPAD / 4, 256, 0, stream>>>(X, cnt, tlist_c, Xg);

    gemm1_kernel<<<MAXT * 16, 256, 0, stream>>>(Xg, GUP, cnt, H);      // 2560 hw blocks
    gemm2_kernel<<<MAXT * 8,  256, 0, stream>>>(H, DP, cnt, Yf);       // 1280 hw blocks

    combine_kernel<<<T_TOK, 256, 0, stream>>>(Yf, cnt, topk_idx, topk_w, posmap, out);
}